// Round 3
// baseline (2468.462 us; speedup 1.0000x reference)
//
#include <hip/hip_runtime.h>
#include <stdint.h>

#define NF 51
#define UNITS 128
#define G3 384
#define OUT_C 102
#define NW 13158            // UNITS*OUT_C + OUT_C
#define GAMMA 28
#define KW_ELEMS 368424     // GAMMA * NW
#define BATCH 8192
#define SEQ_T 64
#define TSTEPS 50           // 64 - LAG(14)
#define NDEC 27
#define BR 32
#define THREADS 512
#define CCONST 0.5413248546129181f  // log(expm1(1.0))

// ---------- JAX threefry2x32 (20 rounds), host+device ----------
__host__ __device__ __forceinline__ void tf2x32(uint32_t k0, uint32_t k1,
    uint32_t x0, uint32_t x1, uint32_t& o0, uint32_t& o1)
{
  uint32_t ks2 = k0 ^ k1 ^ 0x1BD11BDAu;
  x0 += k0; x1 += k1;
#define TF_R(r) { x0 += x1; x1 = (x1 << (r)) | (x1 >> (32 - (r))); x1 ^= x0; }
  TF_R(13) TF_R(15) TF_R(26) TF_R(6)  x0 += k1;  x1 += ks2 + 1u;
  TF_R(17) TF_R(29) TF_R(16) TF_R(24) x0 += ks2; x1 += k0 + 2u;
  TF_R(13) TF_R(15) TF_R(26) TF_R(6)  x0 += k0;  x1 += k1 + 3u;
  TF_R(17) TF_R(29) TF_R(16) TF_R(24) x0 += k1;  x1 += ks2 + 4u;
  TF_R(13) TF_R(15) TF_R(26) TF_R(6)  x0 += ks2; x1 += k0 + 5u;
#undef TF_R
  o0 = x0; o1 = x1;
}

// XLA ErfInv32 (Giles), matches lax.erf_inv on f32
__device__ __forceinline__ float erfinv_f(float x) {
  float w = -log1pf(-x * x);
  float p;
  if (w < 5.0f) {
    w -= 2.5f;
    p = 2.81022636e-08f;
    p = fmaf(p, w, 3.43273939e-07f);
    p = fmaf(p, w, -3.5233877e-06f);
    p = fmaf(p, w, -4.39150654e-06f);
    p = fmaf(p, w, 0.00021858087f);
    p = fmaf(p, w, -0.00125372503f);
    p = fmaf(p, w, -0.00417768164f);
    p = fmaf(p, w, 0.246640727f);
    p = fmaf(p, w, 1.50140941f);
  } else {
    w = sqrtf(w) - 3.0f;
    p = -0.000200214257f;
    p = fmaf(p, w, 0.000100950558f);
    p = fmaf(p, w, 0.00134934322f);
    p = fmaf(p, w, -0.00367342844f);
    p = fmaf(p, w, 0.00573950773f);
    p = fmaf(p, w, -0.0076224613f);
    p = fmaf(p, w, 0.00943887047f);
    p = fmaf(p, w, 1.00167406f);
    p = fmaf(p, w, 2.83297682f);
  }
  return p * x;
}

// jax.random.normal element i — partitionable threefry, 32-bit path:
//   counts1, counts2 = hi/lo words of 64-bit iota  (hi = 0 for our sizes)
//   bits1, bits2 = threefry2x32(key, counts1, counts2)
//   bits = bits1 ^ bits2          <-- XOR of the two output lanes
// (R1 tried pair-split original scheme: absmax 0.125;
//  R2 tried truncate-to-bits2:          absmax 0.121)
__device__ __forceinline__ float jax_normal(uint32_t k0, uint32_t k1, uint32_t i)
{
  uint32_t y0, y1;
  tf2x32(k0, k1, 0u, i, y0, y1);
  uint32_t bits = y0 ^ y1;
  uint32_t fb = (bits >> 9) | 0x3f800000u;
  float f = __uint_as_float(fb) - 1.0f;       // [0,1)
  const float lo = -0.99999994f;              // nextafter(-1,0) f32
  const float d  = 1.99999994f;               // 1 - lo
  float u = __fadd_rn(__fmul_rn(f, d), lo);   // match XLA mul+add (no fma)
  u = fmaxf(lo, u);
  return 1.41421354f * erfinv_f(u);           // np.float32(sqrt(2))
}

__device__ __forceinline__ float softplus_f(float x) {
  return fmaxf(x, 0.0f) + log1pf(expf(-fabsf(x)));
}
__device__ __forceinline__ float sigmoid_f(float x) {
  return 1.0f / (1.0f + expf(-x));
}

// ---------- kernel 1: sample the 28 decoder weight sets into ws ----------
__global__ void sample_w_kernel(const float* __restrict__ post_loc,
                                const float* __restrict__ post_rho,
                                float* __restrict__ wout,
                                uint32_t kw0, uint32_t kw1)
{
  int i = blockIdx.x * 256 + threadIdx.x;
  if (i >= KW_ELEMS) return;
  int widx = i % NW;
  float eps = jax_normal(kw0, kw1, (uint32_t)i);
  float sc = 1e-5f + 0.02f * softplus_f(CCONST + post_rho[widx]);
  wout[i] = fmaf(sc, eps, post_loc[widx]);
}

// ---------- kernel 2: full recurrent model, one block = 32 batch rows ----------
__global__ __launch_bounds__(THREADS, 2) void irnn_main(
    const float* __restrict__ x,     // (8192, 64, 51)
    const float* __restrict__ Wx,    // (51, 384)
    const float* __restrict__ Wh,    // (128, 384)
    const float* __restrict__ gbias, // (2, 384)
    const float* __restrict__ Wdec,  // (28, 13158) sampled
    float* __restrict__ out,         // (8192, 28, 102)
    uint32_t ks0, uint32_t ks1)
{
  __shared__ float h_lds[BR][UNITS];
  __shared__ float s_lds[BR][NF + 1];
  __shared__ float t_lds[BR][OUT_C];

  const int tid = threadIdx.x;
  const int b0 = blockIdx.x * BR;
  const int lane = tid & 63;
  const int rg = tid >> 6;          // 0..7 -> 4 rows each
  const int r0 = rg * 4;
  const int u0 = lane;
  const int u1 = lane + 64;

  // gate biases, held in registers for the whole kernel
  const float bz[2]  = { gbias[u0] + gbias[G3 + u0],
                         gbias[u1] + gbias[G3 + u1] };
  const float brg[2] = { gbias[UNITS + u0] + gbias[G3 + UNITS + u0],
                         gbias[UNITS + u1] + gbias[G3 + UNITS + u1] };
  const float bxh[2] = { gbias[2*UNITS + u0], gbias[2*UNITS + u1] };
  const float brh[2] = { gbias[G3 + 2*UNITS + u0], gbias[G3 + 2*UNITS + u1] };

  float hreg[4][2] = {{0.f,0.f},{0.f,0.f},{0.f,0.f},{0.f,0.f}};
  for (int i = tid; i < BR * UNITS; i += THREADS) (&h_lds[0][0])[i] = 0.f;
  __syncthreads();

  // one GRU step: reads h_lds + s_lds (+ global Wh/Wx), updates hreg
  auto gru_update = [&]() {
    float az[4][2] = {}, ar[4][2] = {}, axh[4][2] = {}, arh[4][2] = {};
    #pragma unroll 4
    for (int k = 0; k < UNITS; ++k) {
      const float* wrow = Wh + k * G3;
      float wz_[2] = { wrow[u0],           wrow[u1] };
      float wr_[2] = { wrow[UNITS + u0],   wrow[UNITS + u1] };
      float wh_[2] = { wrow[2*UNITS + u0], wrow[2*UNITS + u1] };
      #pragma unroll
      for (int r = 0; r < 4; ++r) {
        float hv = h_lds[r0 + r][k];
        #pragma unroll
        for (int j = 0; j < 2; ++j) {
          az[r][j]  = fmaf(hv, wz_[j], az[r][j]);
          ar[r][j]  = fmaf(hv, wr_[j], ar[r][j]);
          arh[r][j] = fmaf(hv, wh_[j], arh[r][j]);
        }
      }
    }
    #pragma unroll 3
    for (int k = 0; k < NF; ++k) {
      const float* wrow = Wx + k * G3;
      float wz_[2] = { wrow[u0],           wrow[u1] };
      float wr_[2] = { wrow[UNITS + u0],   wrow[UNITS + u1] };
      float wh_[2] = { wrow[2*UNITS + u0], wrow[2*UNITS + u1] };
      #pragma unroll
      for (int r = 0; r < 4; ++r) {
        float sv = s_lds[r0 + r][k];
        #pragma unroll
        for (int j = 0; j < 2; ++j) {
          az[r][j]  = fmaf(sv, wz_[j], az[r][j]);
          ar[r][j]  = fmaf(sv, wr_[j], ar[r][j]);
          axh[r][j] = fmaf(sv, wh_[j], axh[r][j]);
        }
      }
    }
    #pragma unroll
    for (int r = 0; r < 4; ++r) {
      #pragma unroll
      for (int j = 0; j < 2; ++j) {
        float z  = sigmoid_f(az[r][j] + bz[j]);
        float rr = sigmoid_f(ar[r][j] + brg[j]);
        float hh = tanhf(axh[r][j] + bxh[j] + rr * (arh[r][j] + brh[j]));
        hreg[r][j] = z * hreg[r][j] + (1.0f - z) * hh;
      }
    }
  };

  auto write_h = [&]() {
    #pragma unroll
    for (int r = 0; r < 4; ++r) {
      h_lds[r0 + r][u0] = hreg[r][0];
      h_lds[r0 + r][u1] = hreg[r][1];
    }
  };

  // sampled head: t = h @ K_g + b_g ; writes raw t to t_lds and
  // transformed (loc | 1e-5 + .05*softplus(C+t)) to global out
  const int tc  = tid & 127;   // col 0..127 (active < 102)
  const int trg = tid >> 7;    // 0..3 -> 8 rows each
  auto tgemm = [&](int g) {
    if (tc < OUT_C) {
      const float* K = Wdec + (size_t)g * NW;
      float acc[8] = {};
      #pragma unroll 4
      for (int k = 0; k < UNITS; ++k) {
        float kv = K[k * OUT_C + tc];
        #pragma unroll
        for (int r = 0; r < 8; ++r)
          acc[r] = fmaf(h_lds[trg * 8 + r][k], kv, acc[r]);
      }
      float kb = K[UNITS * OUT_C + tc];
      #pragma unroll
      for (int r = 0; r < 8; ++r) {
        float tv = acc[r] + kb;
        t_lds[trg * 8 + r][tc] = tv;
        float ov = (tc < NF) ? tv
                             : (1e-5f + 0.05f * softplus_f(CCONST + tv));
        out[(size_t)(b0 + trg * 8 + r) * (GAMMA * OUT_C) + g * OUT_C + tc] = ov;
      }
    }
  };

  // decoder input: s = loc + scale * eps_s[j],  eps_s shape (27, 8192, 51)
  auto sphase = [&](int j) {
    for (int idx = tid; idx < BR * NF; idx += THREADS) {
      int r = idx / NF, f = idx - r * NF;
      float loc = t_lds[r][f];
      float sc = 1e-5f + 0.05f * softplus_f(CCONST + t_lds[r][NF + f]);
      uint32_t gi = (uint32_t)((j * BATCH + b0 + r) * NF + f);
      float es = jax_normal(ks0, ks1, gi);
      s_lds[r][f] = fmaf(sc, es, loc);
    }
  };

  // ---- encoder: 50 steps over x[:, t, :] ----
  for (int t = 0; t < TSTEPS; ++t) {
    for (int idx = tid; idx < BR * NF; idx += THREADS) {
      int r = idx / NF, f = idx - r * NF;
      s_lds[r][f] = x[(size_t)(b0 + r) * (SEQ_T * NF) + t * NF + f];
    }
    __syncthreads();      // s_lds (and previous h writes) visible
    gru_update();
    __syncthreads();      // all reads of h_lds done
    write_h();
  }
  __syncthreads();
  tgemm(0);
  __syncthreads();

  // ---- decoder: 27 steps ----
  for (int j = 0; j < NDEC; ++j) {
    sphase(j);
    __syncthreads();
    gru_update();
    __syncthreads();
    write_h();
    __syncthreads();
    tgemm(j + 1);
    __syncthreads();
  }
}

extern "C" void kernel_launch(void* const* d_in, const int* in_sizes, int n_in,
                              void* d_out, int out_size, void* d_ws, size_t ws_size,
                              hipStream_t stream)
{
  const float* x    = (const float*)d_in[0];
  const float* gk   = (const float*)d_in[1];
  const float* grk  = (const float*)d_in[2];
  const float* gb   = (const float*)d_in[3];
  const float* ploc = (const float*)d_in[4];
  const float* prho = (const float*)d_in[5];
  float* wdec = (float*)d_ws;   // needs 368424*4 = 1.47 MB

  // keys: fold_in(key(42), d) = threefry2x32(key=[0,42], counts=[0, d])
  // (threefry_seed(d) = [0, d]; size-2 count splits as x0=[0], x1=[d];
  //  fold_in path is partitionable-flag-independent)
  uint32_t kw0, kw1, ksd0, ksd1;
  tf2x32(0u, 42u, 0u, 0u, kw0, kw1);
  tf2x32(0u, 42u, 0u, 1u, ksd0, ksd1);

  sample_w_kernel<<<(KW_ELEMS + 255) / 256, 256, 0, stream>>>(ploc, prho, wdec, kw0, kw1);
  irnn_main<<<BATCH / BR, THREADS, 0, stream>>>(x, gk, grk, gb, wdec,
                                                (float*)d_out, ksd0, ksd1);
}